// Round 1
// baseline (11888.395 us; speedup 1.0000x reference)
//
#include <hip/hip_runtime.h>

// Problem constants
constexpr int S   = 10;
constexpr int Bsz = 16384;
constexpr int LAG = 5;
constexpr int H   = 512;
constexpr int G4  = 4 * H;          // 2048
constexpr int F   = 5;
constexpr int BH  = Bsz * H;        // 8388608
constexpr int OUT_HN = Bsz * (S + F);      // 245760
constexpr int OUT_CN = OUT_HN + 2 * BH;    // 17022976

__device__ __forceinline__ float sigf(float x) {
    return 1.0f / (1.0f + __expf(-x));
}
__device__ __forceinline__ float tanh_fast(float x) {
    // tanh(x) = 1 - 2/(e^{2x}+1); saturates correctly at +/-inf
    float e = __expf(2.0f * x);
    return 1.0f - 2.0f / (e + 1.0f);
}

// ---------------------------------------------------------------------------
// Prep: reorder weight rows to r = n*4 + gate, fold input chain:
//   A0 = Wih0 @ W_in  [2048,5],  b0 = Wih0@b_in + bih0 + bhh0
//   W1cat = [Wih1 | Whh1] (K=1024), b1 = bih1 + bhh1
// ---------------------------------------------------------------------------
__global__ __launch_bounds__(256)
void prep_kernel(const float* __restrict__ W_in,  const float* __restrict__ b_in,
                 const float* __restrict__ Wih0,  const float* __restrict__ Whh0,
                 const float* __restrict__ bih0,  const float* __restrict__ bhh0,
                 const float* __restrict__ Wih1,  const float* __restrict__ Whh1,
                 const float* __restrict__ bih1,  const float* __restrict__ bhh1,
                 float* __restrict__ W0r, float* __restrict__ W1r,
                 float* __restrict__ A0r, float* __restrict__ b0r,
                 float* __restrict__ b1r)
{
    const int r   = blockIdx.x;          // 0..2047
    const int n   = r >> 2;
    const int g   = r & 3;
    const int src = g * H + n;           // original row (gate-major)
    const int tid = threadIdx.x;

    for (int k = tid; k < H; k += 256)
        W0r[r * H + k] = Whh0[src * H + k];
    for (int k = tid; k < 2 * H; k += 256)
        W1r[r * 2 * H + k] = (k < H) ? Wih1[src * H + k] : Whh1[src * H + (k - H)];

    if (tid < LAG) {
        float s = 0.f;
        for (int h = 0; h < H; ++h) s += Wih0[src * H + h] * W_in[h * LAG + tid];
        A0r[r * LAG + tid] = s;
    } else if (tid == 5) {
        float s = 0.f;
        for (int h = 0; h < H; ++h) s += Wih0[src * H + h] * b_in[h];
        b0r[r] = s + bih0[src] + bhh0[src];
    } else if (tid == 6) {
        b1r[r] = bih1[src] + bhh1[src];
    }
}

// ---------------------------------------------------------------------------
// Fused GEMM + LSTM cell.
//   gates[b, r] = sum_k A[b,k] * W[r,k] + bias[r] (+ x-dot for layer 0)
// A is given as up to two [B,512] segments (h0 | h1). W rows are r-ordered
// (r = n*4+gate) so each thread's 8 columns = 2 hidden units x 4 gates.
// Tile: 128x128, BK=16, 256 threads, 8x8 per thread.
// ---------------------------------------------------------------------------
__global__ __launch_bounds__(256)
void lstm_gemm(const float* __restrict__ Aseg0,
               const float* __restrict__ Aseg1,
               int nkt,                       // k-tiles of 16 (0, 32 or 64)
               const float* __restrict__ W, int ldw,
               const float* __restrict__ bias,
               const float* __restrict__ xs,   // [B,5] or null (layer0 only)
               const float* __restrict__ A0r,  // [2048,5] or null
               const float* __restrict__ c_in, // null => c_old = 0
               float* __restrict__ c_out,
               float* __restrict__ h_out)
{
    __shared__ float As[16 * 132];
    __shared__ float Bs[16 * 132];

    const int tid = threadIdx.x;
    const int tx  = tid & 15;        // N direction (16 x 8 = 128 cols)
    const int ty  = tid >> 4;        // M direction (16 x 8 = 128 rows)
    const int bN  = blockIdx.x * 128;
    const int bM  = blockIdx.y * 128;

    float acc[8][8];
    #pragma unroll
    for (int i = 0; i < 8; ++i)
        #pragma unroll
        for (int j = 0; j < 8; ++j) acc[i][j] = 0.f;

    const int lrow = tid >> 2;        // 0..63
    const int lk4  = (tid & 3) * 4;   // 0,4,8,12

    for (int kt = 0; kt < nkt; ++kt) {
        const float* Ab;
        int k0;
        if (kt < 32) { Ab = Aseg0; k0 = kt * 16; }
        else         { Ab = Aseg1; k0 = (kt - 32) * 16; }
        const int kw = kt * 16;

        const float4 av0 = *reinterpret_cast<const float4*>(&Ab[(bM + lrow)      * H + k0 + lk4]);
        const float4 av1 = *reinterpret_cast<const float4*>(&Ab[(bM + 64 + lrow) * H + k0 + lk4]);
        const float4 bv0 = *reinterpret_cast<const float4*>(&W[(size_t)(bN + lrow)      * ldw + kw + lk4]);
        const float4 bv1 = *reinterpret_cast<const float4*>(&W[(size_t)(bN + 64 + lrow) * ldw + kw + lk4]);

        __syncthreads();
        As[(lk4 + 0) * 132 + lrow] = av0.x;
        As[(lk4 + 1) * 132 + lrow] = av0.y;
        As[(lk4 + 2) * 132 + lrow] = av0.z;
        As[(lk4 + 3) * 132 + lrow] = av0.w;
        As[(lk4 + 0) * 132 + 64 + lrow] = av1.x;
        As[(lk4 + 1) * 132 + 64 + lrow] = av1.y;
        As[(lk4 + 2) * 132 + 64 + lrow] = av1.z;
        As[(lk4 + 3) * 132 + 64 + lrow] = av1.w;
        Bs[(lk4 + 0) * 132 + lrow] = bv0.x;
        Bs[(lk4 + 1) * 132 + lrow] = bv0.y;
        Bs[(lk4 + 2) * 132 + lrow] = bv0.z;
        Bs[(lk4 + 3) * 132 + lrow] = bv0.w;
        Bs[(lk4 + 0) * 132 + 64 + lrow] = bv1.x;
        Bs[(lk4 + 1) * 132 + 64 + lrow] = bv1.y;
        Bs[(lk4 + 2) * 132 + 64 + lrow] = bv1.z;
        Bs[(lk4 + 3) * 132 + 64 + lrow] = bv1.w;
        __syncthreads();

        #pragma unroll
        for (int k = 0; k < 16; ++k) {
            const float4 a0 = *reinterpret_cast<const float4*>(&As[k * 132 + ty * 8]);
            const float4 a1 = *reinterpret_cast<const float4*>(&As[k * 132 + ty * 8 + 4]);
            const float4 b0 = *reinterpret_cast<const float4*>(&Bs[k * 132 + tx * 8]);
            const float4 b1 = *reinterpret_cast<const float4*>(&Bs[k * 132 + tx * 8 + 4]);
            const float am[8] = {a0.x, a0.y, a0.z, a0.w, a1.x, a1.y, a1.z, a1.w};
            const float bn[8] = {b0.x, b0.y, b0.z, b0.w, b1.x, b1.y, b1.z, b1.w};
            #pragma unroll
            for (int i = 0; i < 8; ++i)
                #pragma unroll
                for (int j = 0; j < 8; ++j)
                    acc[i][j] = fmaf(am[i], bn[j], acc[i][j]);
        }
    }

    // ---------------- epilogue: bias + x-dot + LSTM cell ----------------
    const int r0 = bN + tx * 8;
    float bias8[8];
    #pragma unroll
    for (int j = 0; j < 8; ++j) bias8[j] = bias[r0 + j];

    float a0r[8][LAG];
    if (xs) {
        #pragma unroll
        for (int j = 0; j < 8; ++j)
            for (int l = 0; l < LAG; ++l) a0r[j][l] = A0r[(r0 + j) * LAG + l];
    }

    #pragma unroll
    for (int i = 0; i < 8; ++i) {
        const int b = bM + ty * 8 + i;
        float g8[8];
        #pragma unroll
        for (int j = 0; j < 8; ++j) g8[j] = acc[i][j] + bias8[j];
        if (xs) {
            float xl[LAG];
            #pragma unroll
            for (int l = 0; l < LAG; ++l) xl[l] = xs[b * LAG + l];
            #pragma unroll
            for (int j = 0; j < 8; ++j)
                for (int l = 0; l < LAG; ++l)
                    g8[j] = fmaf(xl[l], a0r[j][l], g8[j]);
        }
        #pragma unroll
        for (int u = 0; u < 2; ++u) {
            const int n   = (r0 >> 2) + u;
            const float ig = sigf(g8[u * 4 + 0]);
            const float fg = sigf(g8[u * 4 + 1]);
            const float gg = tanh_fast(g8[u * 4 + 2]);
            const float og = sigf(g8[u * 4 + 3]);
            const float cold = c_in ? c_in[b * H + n] : 0.f;
            const float cnew = fg * cold + ig * gg;
            const float hh   = og * tanh_fast(cnew);
            c_out[b * H + n] = cnew;
            h_out[b * H + n] = hh;
        }
    }
}

// ---------------------------------------------------------------------------
// Per-step scalar head (+ forecast head on the last step).
// One wave per batch row.
// ---------------------------------------------------------------------------
__global__ __launch_bounds__(256)
void out_head(const float* __restrict__ h1,
              const float* __restrict__ W_out, const float* __restrict__ b_out,
              const float* __restrict__ W_f,   const float* __restrict__ b_f,
              float* __restrict__ out, int s, int last)
{
    const int wave = threadIdx.x >> 6;
    const int lane = threadIdx.x & 63;
    const int b    = blockIdx.x * 4 + wave;

    const float* hrow = h1 + (size_t)b * H;
    const float4 t0 = *reinterpret_cast<const float4*>(&hrow[lane * 8]);
    const float4 t1 = *reinterpret_cast<const float4*>(&hrow[lane * 8 + 4]);
    const float h8[8] = {t0.x, t0.y, t0.z, t0.w, t1.x, t1.y, t1.z, t1.w};

    {
        const float4 w0 = *reinterpret_cast<const float4*>(&W_out[lane * 8]);
        const float4 w1 = *reinterpret_cast<const float4*>(&W_out[lane * 8 + 4]);
        const float w8[8] = {w0.x, w0.y, w0.z, w0.w, w1.x, w1.y, w1.z, w1.w};
        float v = 0.f;
        #pragma unroll
        for (int i = 0; i < 8; ++i) v = fmaf(h8[i], w8[i], v);
        #pragma unroll
        for (int off = 32; off > 0; off >>= 1) v += __shfl_down(v, off, 64);
        if (lane == 0) out[b * (S + F) + s] = v + b_out[0];
    }

    if (last) {
        for (int f = 0; f < F; ++f) {
            const float4 w0 = *reinterpret_cast<const float4*>(&W_f[f * H + lane * 8]);
            const float4 w1 = *reinterpret_cast<const float4*>(&W_f[f * H + lane * 8 + 4]);
            const float w8[8] = {w0.x, w0.y, w0.z, w0.w, w1.x, w1.y, w1.z, w1.w};
            float v = 0.f;
            #pragma unroll
            for (int i = 0; i < 8; ++i) v = fmaf(h8[i], w8[i], v);
            #pragma unroll
            for (int off = 32; off > 0; off >>= 1) v += __shfl_down(v, off, 64);
            if (lane == 0) out[b * (S + F) + S + f] = v + b_f[f];
        }
    }
}

// ---------------------------------------------------------------------------
extern "C" void kernel_launch(void* const* d_in, const int* in_sizes, int n_in,
                              void* d_out, int out_size, void* d_ws, size_t ws_size,
                              hipStream_t stream)
{
    const float* x     = (const float*)d_in[0];
    const float* W_in  = (const float*)d_in[1];
    const float* b_in  = (const float*)d_in[2];
    const float* Wih0  = (const float*)d_in[3];
    const float* Whh0  = (const float*)d_in[4];
    const float* bih0  = (const float*)d_in[5];
    const float* bhh0  = (const float*)d_in[6];
    const float* Wih1  = (const float*)d_in[7];
    const float* Whh1  = (const float*)d_in[8];
    const float* bih1  = (const float*)d_in[9];
    const float* bhh1  = (const float*)d_in[10];
    const float* W_out = (const float*)d_in[11];
    const float* b_out = (const float*)d_in[12];
    const float* W_f   = (const float*)d_in[13];
    const float* b_f   = (const float*)d_in[14];

    float* out = (float*)d_out;
    float* ws  = (float*)d_ws;

    // workspace layout (79.75 MB of floats)
    float* h0_ws = ws;
    float* h1_ws = ws + BH;
    float* W0r   = ws + 2 * BH;
    float* W1r   = W0r + G4 * H;
    float* A0r   = W1r + G4 * 2 * H;
    float* b0r   = A0r + G4 * LAG;
    float* b1r   = b0r + G4;

    // d_out sections double as state buffers (step 9 lands in place)
    float* h0_do = out + OUT_HN;
    float* h1_do = out + OUT_HN + BH;
    float* c0    = out + OUT_CN;        // c updated in place
    float* c1    = out + OUT_CN + BH;

    prep_kernel<<<dim3(G4), dim3(256), 0, stream>>>(
        W_in, b_in, Wih0, Whh0, bih0, bhh0, Wih1, Whh1, bih1, bhh1,
        W0r, W1r, A0r, b0r, b1r);

    float* h0buf[2] = {h0_ws, h0_do};   // step s writes buf[s&1]; step 9 -> d_out
    float* h1buf[2] = {h1_ws, h1_do};

    const dim3 grid(G4 / 128, Bsz / 128);   // (16, 128)
    const dim3 blk(256);

    for (int s = 0; s < S; ++s) {
        const bool first = (s == 0);
        const bool last  = (s == S - 1);

        const float* h0_in = first ? nullptr : h0buf[(s - 1) & 1];
        float* h0_out = h0buf[s & 1];
        lstm_gemm<<<grid, blk, 0, stream>>>(
            h0_in, nullptr, first ? 0 : 32, W0r, H, b0r,
            x + (size_t)s * Bsz * LAG, A0r,
            first ? nullptr : c0, c0, h0_out);

        const float* h1_in = first ? nullptr : h1buf[(s - 1) & 1];
        float* h1_out = h1buf[s & 1];
        lstm_gemm<<<grid, blk, 0, stream>>>(
            h0_out, h1_in, first ? 32 : 64, W1r, 2 * H, b1r,
            nullptr, nullptr,
            first ? nullptr : c1, c1, h1_out);

        out_head<<<dim3(Bsz / 4), blk, 0, stream>>>(
            h1_out, W_out, b_out, W_f, b_f, out, s, last ? 1 : 0);
    }
}

// Round 2
// 2117.830 us; speedup vs baseline: 5.6135x; 5.6135x over previous
//
#include <hip/hip_runtime.h>
#include <hip/hip_bf16.h>

constexpr int S   = 10;
constexpr int Bsz = 16384;
constexpr int LAG = 5;
constexpr int H   = 512;
constexpr int G4  = 4 * H;            // 2048
constexpr int F   = 5;
constexpr int BH  = Bsz * H;          // 8388608
constexpr int OUT_HN = Bsz * (S + F); // 245760
constexpr int OUT_CN = OUT_HN + 2 * BH;

typedef __attribute__((ext_vector_type(8))) short short8;   // 8 bf16 = 4 VGPRs
typedef __attribute__((ext_vector_type(4))) float f32x4;

__device__ __forceinline__ float sigf(float x) { return 1.0f / (1.0f + __expf(-x)); }
__device__ __forceinline__ float tanh_fast(float x) {
    float e = __expf(2.0f * x);
    return 1.0f - 2.0f / (e + 1.0f);
}

__device__ __forceinline__ void gload_lds16(const void* g, void* l) {
    __builtin_amdgcn_global_load_lds(
        (const __attribute__((address_space(1))) unsigned int*)g,
        (__attribute__((address_space(3))) unsigned int*)l, 16, 0, 0);
}

// ---------------------------------------------------------------------------
// Prep (gate-major, no row reorder):
//   W0b = bf16(Whh0) [2048,512];  W1b = bf16([Wih1 | Whh1]) [2048,1024]
//   A0r = Wih0 @ W_in [2048,5];   b0 = Wih0@b_in + bih0 + bhh0;  b1 = bih1+bhh1
// ---------------------------------------------------------------------------
__global__ __launch_bounds__(256)
void prep_kernel(const float* __restrict__ W_in,  const float* __restrict__ b_in,
                 const float* __restrict__ Wih0,  const float* __restrict__ Whh0,
                 const float* __restrict__ bih0,  const float* __restrict__ bhh0,
                 const float* __restrict__ Wih1,  const float* __restrict__ Whh1,
                 const float* __restrict__ bih1,  const float* __restrict__ bhh1,
                 __hip_bfloat16* __restrict__ W0b, __hip_bfloat16* __restrict__ W1b,
                 float* __restrict__ A0r, float* __restrict__ b0r,
                 float* __restrict__ b1r)
{
    const int r   = blockIdx.x;   // 0..2047, gate-major (PyTorch order)
    const int tid = threadIdx.x;

    for (int k = tid; k < H; k += 256)
        W0b[r * H + k] = __float2bfloat16(Whh0[r * H + k]);
    for (int k = tid; k < 2 * H; k += 256)
        W1b[r * 2 * H + k] = __float2bfloat16(
            (k < H) ? Wih1[r * H + k] : Whh1[r * H + (k - H)]);

    if (tid < LAG) {
        float s = 0.f;
        for (int h = 0; h < H; ++h) s += Wih0[r * H + h] * W_in[h * LAG + tid];
        A0r[r * LAG + tid] = s;
    } else if (tid == 5) {
        float s = 0.f;
        for (int h = 0; h < H; ++h) s += Wih0[r * H + h] * b_in[h];
        b0r[r] = s + bih0[r] + bhh0[r];
    } else if (tid == 6) {
        b1r[r] = bih1[r] + bhh1[r];
    }
}

// ---------------------------------------------------------------------------
// MFMA GEMM + fused LSTM cell.
// gates[b,r] = sum_k A[b,k]*W[r,k] + bias[r] (+ x@A0r fold for layer 0)
// Block tile: 128 rows (batch) x 128 cols = 32 hidden units x 4 gates.
// 4 waves in 2x2; each wave: 64 rows x (16 units x 4 gates).
// MFMA 16x16x32 bf16; each N-tile of 16 = one gate at the same unit range,
// so a lane holds all 4 gates of a single unit n -> cell in registers.
// ---------------------------------------------------------------------------
__global__ __launch_bounds__(256)
void lstm_gemm(const __hip_bfloat16* __restrict__ Abase0, // k-tiles [0,16)
               const __hip_bfloat16* __restrict__ Abase1, // k-tiles [16,32)
               int nkt,                                   // 0, 16 or 32
               const __hip_bfloat16* __restrict__ W, int ldw,
               const float* __restrict__ bias,
               const float* __restrict__ xs,   // [B,5] or null
               const float* __restrict__ A0r,  // [2048,5] or null
               const float* __restrict__ c_in, // null => c_old = 0
               float* __restrict__ c_out,
               float* __restrict__ h32_out,    // fp32 h (d_out h_n slot)
               __hip_bfloat16* __restrict__ hb16_out, // bf16 h concat buffer
               int hcol)                       // 0 (layer0) or 512 (layer1)
{
    __shared__ __align__(16) short As[128 * 32];  // [row][k] 64B rows
    __shared__ __align__(16) short Bs[128 * 32];  // [c_local = g*32+nn][k]
    __shared__ float xls[128 * LAG];
    __shared__ float a0ls[128 * LAG];

    const int tid  = threadIdx.x;
    const int lane = tid & 63;
    const int quad = lane >> 4;
    const int li   = lane & 15;
    const int ww   = tid >> 6;
    const int wy   = ww >> 1;   // M dir (2 waves)
    const int wx   = ww & 1;    // N dir (2 waves)

    const int bM = blockIdx.y * 128;   // batch base
    const int cn = blockIdx.x * 32;    // hidden-unit base (32 units/block)

    const bool has_x = (xs != nullptr);
    if (has_x) {
        for (int i = tid; i < 128 * LAG; i += 256) {
            const int row = i / LAG, l = i % LAG;
            xls[i] = xs[(size_t)(bM + row) * LAG + l];
        }
        for (int i = tid; i < 128 * LAG; i += 256) {
            const int cl = i / LAG, l = i % LAG;      // cl = g*32+nn
            const int r  = (cl >> 5) * H + cn + (cl & 31);
            a0ls[i] = A0r[r * LAG + l];
        }
    }
    __syncthreads();

    f32x4 acc[4][4];  // [m-tile][gate]
    #pragma unroll
    for (int i = 0; i < 4; ++i)
        #pragma unroll
        for (int j = 0; j < 4; ++j) acc[i][j] = (f32x4){0.f, 0.f, 0.f, 0.f};

    for (int kt = 0; kt < nkt; ++kt) {
        const __hip_bfloat16* Ab = (kt < 16) ? Abase0 : Abase1;
        const int kb = kt * 32;

        __syncthreads();
        #pragma unroll
        for (int r = 0; r < 2; ++r) {
            const int idx = r * 256 + tid;
            const int row = idx >> 2;
            const int kc  = (idx & 3) * 8;
            gload_lds16(Ab + (size_t)(bM + row) * 1024 + kb + kc, &As[idx * 8]);
        }
        #pragma unroll
        for (int r = 0; r < 2; ++r) {
            const int idx = r * 256 + tid;
            const int cl  = idx >> 2;                 // c_local
            const int kc  = (idx & 3) * 8;
            const int rr  = (cl >> 5) * H + cn + (cl & 31);
            gload_lds16(W + (size_t)rr * ldw + kb + kc, &Bs[idx * 8]);
        }
        __syncthreads();

        short8 af[4], bf[4];
        #pragma unroll
        for (int mt = 0; mt < 4; ++mt)
            af[mt] = *(const short8*)&As[(wy * 64 + mt * 16 + li) * 32 + quad * 8];
        #pragma unroll
        for (int g = 0; g < 4; ++g)
            bf[g] = *(const short8*)&Bs[(g * 32 + wx * 16 + li) * 32 + quad * 8];
        #pragma unroll
        for (int mt = 0; mt < 4; ++mt)
            #pragma unroll
            for (int g = 0; g < 4; ++g)
                acc[mt][g] = __builtin_amdgcn_mfma_f32_16x16x32_bf16(
                    af[mt], bf[g], acc[mt][g], 0, 0, 0);
    }

    // ---------------- epilogue: bias + x-fold + LSTM cell ----------------
    const int n = cn + wx * 16 + li;        // this lane's hidden unit
    float bias4[4], a0reg[4][LAG];
    #pragma unroll
    for (int g = 0; g < 4; ++g) bias4[g] = bias[g * H + n];
    if (has_x) {
        #pragma unroll
        for (int g = 0; g < 4; ++g)
            #pragma unroll
            for (int l = 0; l < LAG; ++l)
                a0reg[g][l] = a0ls[(g * 32 + wx * 16 + li) * LAG + l];
    }

    #pragma unroll
    for (int mt = 0; mt < 4; ++mt) {
        #pragma unroll
        for (int reg = 0; reg < 4; ++reg) {
            const int b_loc = wy * 64 + mt * 16 + quad * 4 + reg;
            const int b     = bM + b_loc;
            float g4[4];
            #pragma unroll
            for (int g = 0; g < 4; ++g) g4[g] = acc[mt][g][reg] + bias4[g];
            if (has_x) {
                #pragma unroll
                for (int l = 0; l < LAG; ++l) {
                    const float xv = xls[b_loc * LAG + l];
                    #pragma unroll
                    for (int g = 0; g < 4; ++g) g4[g] = fmaf(xv, a0reg[g][l], g4[g]);
                }
            }
            const float ig = sigf(g4[0]);
            const float fg = sigf(g4[1]);
            const float gg = tanh_fast(g4[2]);
            const float og = sigf(g4[3]);
            const float cold = c_in ? c_in[(size_t)b * H + n] : 0.f;
            const float cnew = fg * cold + ig * gg;
            const float hh   = og * tanh_fast(cnew);
            c_out[(size_t)b * H + n]  = cnew;
            h32_out[(size_t)b * H + n] = hh;
            hb16_out[(size_t)b * 1024 + hcol + n] = __float2bfloat16(hh);
        }
    }
}

// ---------------------------------------------------------------------------
// Per-step scalar head (+ forecast head on last step). One wave per row.
// ---------------------------------------------------------------------------
__global__ __launch_bounds__(256)
void out_head(const float* __restrict__ h1,
              const float* __restrict__ W_out, const float* __restrict__ b_out,
              const float* __restrict__ W_f,   const float* __restrict__ b_f,
              float* __restrict__ out, int s, int last)
{
    const int wave = threadIdx.x >> 6;
    const int lane = threadIdx.x & 63;
    const int b    = blockIdx.x * 4 + wave;

    const float* hrow = h1 + (size_t)b * H;
    const float4 t0 = *reinterpret_cast<const float4*>(&hrow[lane * 8]);
    const float4 t1 = *reinterpret_cast<const float4*>(&hrow[lane * 8 + 4]);
    const float h8[8] = {t0.x, t0.y, t0.z, t0.w, t1.x, t1.y, t1.z, t1.w};

    {
        const float4 w0 = *reinterpret_cast<const float4*>(&W_out[lane * 8]);
        const float4 w1 = *reinterpret_cast<const float4*>(&W_out[lane * 8 + 4]);
        const float w8[8] = {w0.x, w0.y, w0.z, w0.w, w1.x, w1.y, w1.z, w1.w};
        float v = 0.f;
        #pragma unroll
        for (int i = 0; i < 8; ++i) v = fmaf(h8[i], w8[i], v);
        #pragma unroll
        for (int off = 32; off > 0; off >>= 1) v += __shfl_down(v, off, 64);
        if (lane == 0) out[b * (S + F) + s] = v + b_out[0];
    }
    if (last) {
        for (int f = 0; f < F; ++f) {
            const float4 w0 = *reinterpret_cast<const float4*>(&W_f[f * H + lane * 8]);
            const float4 w1 = *reinterpret_cast<const float4*>(&W_f[f * H + lane * 8 + 4]);
            const float w8[8] = {w0.x, w0.y, w0.z, w0.w, w1.x, w1.y, w1.z, w1.w};
            float v = 0.f;
            #pragma unroll
            for (int i = 0; i < 8; ++i) v = fmaf(h8[i], w8[i], v);
            #pragma unroll
            for (int off = 32; off > 0; off >>= 1) v += __shfl_down(v, off, 64);
            if (lane == 0) out[b * (S + F) + S + f] = v + b_f[f];
        }
    }
}

// ---------------------------------------------------------------------------
extern "C" void kernel_launch(void* const* d_in, const int* in_sizes, int n_in,
                              void* d_out, int out_size, void* d_ws, size_t ws_size,
                              hipStream_t stream)
{
    const float* x     = (const float*)d_in[0];
    const float* W_in  = (const float*)d_in[1];
    const float* b_in  = (const float*)d_in[2];
    const float* Wih0  = (const float*)d_in[3];
    const float* Whh0  = (const float*)d_in[4];
    const float* bih0  = (const float*)d_in[5];
    const float* bhh0  = (const float*)d_in[6];
    const float* Wih1  = (const float*)d_in[7];
    const float* Whh1  = (const float*)d_in[8];
    const float* bih1  = (const float*)d_in[9];
    const float* bhh1  = (const float*)d_in[10];
    const float* W_out = (const float*)d_in[11];
    const float* b_out = (const float*)d_in[12];
    const float* W_f   = (const float*)d_in[13];
    const float* b_f   = (const float*)d_in[14];

    float* out = (float*)d_out;
    char*  ws  = (char*)d_ws;

    // workspace layout
    __hip_bfloat16* hcat0 = (__hip_bfloat16*)ws;                    // [B,1024]
    __hip_bfloat16* hcat1 = hcat0 + (size_t)Bsz * 1024;             // [B,1024]
    __hip_bfloat16* W0b   = hcat1 + (size_t)Bsz * 1024;             // [2048,512]
    __hip_bfloat16* W1b   = W0b + (size_t)G4 * H;                   // [2048,1024]
    float* A0r = (float*)(W1b + (size_t)G4 * 2 * H);                // [2048,5]
    float* b0r = A0r + G4 * LAG;
    float* b1r = b0r + G4;

    // d_out sections as state
    float* hn0 = out + OUT_HN;            // h0 fp32 (rewritten each step)
    float* hn1 = out + OUT_HN + BH;       // h1 fp32
    float* c0  = out + OUT_CN;            // c0 in place
    float* c1  = out + OUT_CN + BH;       // c1 in place

    prep_kernel<<<dim3(G4), dim3(256), 0, stream>>>(
        W_in, b_in, Wih0, Whh0, bih0, bhh0, Wih1, Whh1, bih1, bhh1,
        W0b, W1b, A0r, b0r, b1r);

    __hip_bfloat16* hbuf[2] = {hcat0, hcat1};
    const dim3 grid(H / 32, Bsz / 128);   // (16, 128) = 2048 blocks
    const dim3 blk(256);

    for (int s = 0; s < S; ++s) {
        const bool first = (s == 0);
        const bool last  = (s == S - 1);
        __hip_bfloat16* cur  = hbuf[s & 1];
        __hip_bfloat16* prev = hbuf[(s + 1) & 1];

        // layer 0: A = h0_prev (bf16 cols 0..511 of prev), K=512
        lstm_gemm<<<grid, blk, 0, stream>>>(
            prev, prev, first ? 0 : 16, W0b, H, b0r,
            x + (size_t)s * Bsz * LAG, A0r,
            first ? nullptr : c0, c0, hn0, cur, 0);

        // layer 1: A = [h0_cur | h1_prev], K=1024
        lstm_gemm<<<grid, blk, 0, stream>>>(
            cur, prev, first ? 16 : 32, W1b, 2 * H, b1r,
            nullptr, nullptr,
            first ? nullptr : c1, c1, hn1, cur, H);

        out_head<<<dim3(Bsz / 4), blk, 0, stream>>>(
            hn1, W_out, b_out, W_f, b_f, out, s, last ? 1 : 0);
    }
}